// Round 5
// baseline (260.753 us; speedup 1.0000x reference)
//
#include <hip/hip_runtime.h>

constexpr int N_CLASSES = 1000;   // 250 float4 per label row
constexpr int EMBED     = 1024;   // 256 float4 per row; 4 float4 per lane

typedef float floatx4 __attribute__((ext_vector_type(4)));

// ---------------- Kernel 1: one-hot class scan (pure stream) ----------------
// Block per row, thread t < 250 checks 4 classes. Exactly one thread per row
// finds the 1.0 and writes cls[row]. No reduction, no sync, no chains.
__global__ __launch_bounds__(256) void class_scan_kernel(
    const float* __restrict__ labels,
    int* __restrict__ cls_buf)
{
    const int row = blockIdx.x;
    const int t   = threadIdx.x;
    if (t < N_CLASSES / 4) {
        const floatx4* lrow = (const floatx4*)(labels + (size_t)row * N_CLASSES);
        floatx4 v = __builtin_nontemporal_load(lrow + t);
        if (v.x != 0.f || v.y != 0.f || v.z != 0.f || v.w != 0.f) {
            int c = 4 * t;
            if      (v.y != 0.f) c += 1;
            else if (v.z != 0.f) c += 2;
            else if (v.w != 0.f) c += 3;
            cls_buf[row] = c;     // exactly one store per row across the grid
        }
    }
}

// ---------------- Kernel 2: dots (stream + gather, no serial phases) --------
// Wave per row. cls is a broadcast load; feature + proto loads all issue
// back-to-back (8 outstanding), single butterfly at the end.
__global__ __launch_bounds__(256) void angular_dots_kernel(
    const float* __restrict__ features,
    const float* __restrict__ mean_class,
    const int* __restrict__ cls_buf,
    float* __restrict__ partials,
    int n_rows)
{
    const int tid  = threadIdx.x;
    const int lane = tid & 63;
    const int wave = tid >> 6;
    const int row  = blockIdx.x * 4 + wave;

    float res = 0.0f;

    if (row < n_rows) {
        const int cls = __builtin_amdgcn_readfirstlane(cls_buf[row]);

        const floatx4* frow = (const floatx4*)(features + (size_t)row * EMBED);
        const floatx4* prow = (const floatx4*)(mean_class + (size_t)cls * EMBED);

        floatx4 f0 = __builtin_nontemporal_load(frow + lane);
        floatx4 f1 = __builtin_nontemporal_load(frow + lane + 64);
        floatx4 f2 = __builtin_nontemporal_load(frow + lane + 128);
        floatx4 f3 = __builtin_nontemporal_load(frow + lane + 192);
        floatx4 p0 = prow[lane];
        floatx4 p1 = prow[lane + 64];
        floatx4 p2 = prow[lane + 128];
        floatx4 p3 = prow[lane + 192];

        float ff = 0.f, pp = 0.f, fp = 0.f;
        #define DOT3(F, P) \
            ff += F.x*F.x + F.y*F.y + F.z*F.z + F.w*F.w; \
            pp += P.x*P.x + P.y*P.y + P.z*P.z + P.w*P.w; \
            fp += F.x*P.x + F.y*P.y + F.z*P.z + F.w*P.w;
        DOT3(f0, p0) DOT3(f1, p1) DOT3(f2, p2) DOT3(f3, p3)
        #undef DOT3

        #pragma unroll
        for (int msk = 1; msk < 64; msk <<= 1) {
            ff += __shfl_xor(ff, msk, 64);
            pp += __shfl_xor(pp, msk, 64);
            fp += __shfl_xor(fp, msk, 64);
        }
        const float denom = fmaxf(sqrtf(ff), 1e-12f) * fmaxf(sqrtf(pp), 1e-12f);
        res = 1.0f - fp / denom;
    }

    __shared__ float s_red[4];
    if (lane == 0) s_red[wave] = res;
    __syncthreads();
    if (tid == 0)
        partials[blockIdx.x] = s_red[0] + s_red[1] + s_red[2] + s_red[3];
}

// ---------------- Kernel 3: final reduce ----------------
__global__ __launch_bounds__(256) void reduce_partials_kernel(
    const float* __restrict__ partials, int num_partials,
    float* __restrict__ out, float inv_n)
{
    const int tid  = threadIdx.x;
    const int lane = tid & 63;
    const int wave = tid >> 6;
    __shared__ float s_red[4];

    float acc = 0.0f;
    for (int i = tid; i < num_partials; i += 256)
        acc += partials[i];
    #pragma unroll
    for (int msk = 1; msk < 64; msk <<= 1)
        acc += __shfl_xor(acc, msk, 64);
    if (lane == 0) s_red[wave] = acc;
    __syncthreads();
    if (tid == 0)
        out[0] = (s_red[0] + s_red[1] + s_red[2] + s_red[3]) * inv_n;
}

extern "C" void kernel_launch(void* const* d_in, const int* in_sizes, int n_in,
                              void* d_out, int out_size, void* d_ws, size_t ws_size,
                              hipStream_t stream) {
    const float* features   = (const float*)d_in[0];
    const float* labels     = (const float*)d_in[1];
    const float* mean_class = (const float*)d_in[2];
    float* out = (float*)d_out;

    const int n_rows = in_sizes[0] / EMBED;          // 32768
    int* cls_buf    = (int*)d_ws;                    // 128 KB
    float* partials = (float*)d_ws + n_rows;         // 32 KB

    const int dot_blocks = (n_rows + 3) / 4;         // 8192

    class_scan_kernel<<<n_rows, 256, 0, stream>>>(labels, cls_buf);
    angular_dots_kernel<<<dot_blocks, 256, 0, stream>>>(
        features, mean_class, cls_buf, partials, n_rows);
    reduce_partials_kernel<<<1, 256, 0, stream>>>(
        partials, dot_blocks, out, 1.0f / (float)n_rows);
}

// Round 6
// 258.300 us; speedup vs baseline: 1.0095x; 1.0095x over previous
//
#include <hip/hip_runtime.h>

constexpr int N_CLASSES = 1000;   // 250 float4 per label row
constexpr int EMBED     = 1024;   // 256 float4 per row; 4 float4 per lane
constexpr int ROWS_PER_BLOCK = 8; // 4 waves x 2 rows

typedef float floatx4 __attribute__((ext_vector_type(4)));

// Fused, phase-batched: block (256 thr) owns 8 rows.
// Phase A: label scan for all 8 rows (8 independent loads/thread, no reduce,
//          finder writes s_cls[r]).  One barrier.
// Phase B: wave w does rows 2w,2w+1: 8 feature + 8 proto loads per lane all
//          independent -> deep MLP; one 6-deep butterfly per wave.
// => two vmcnt drains per 8 rows instead of per row.
__global__ __launch_bounds__(256) void angular_fused_kernel(
    const float* __restrict__ features,
    const float* __restrict__ labels,
    const float* __restrict__ mean_class,
    float* __restrict__ partials,
    int n_rows)
{
    const int tid  = threadIdx.x;
    const int lane = tid & 63;
    const int wave = tid >> 6;
    const int row0 = blockIdx.x * ROWS_PER_BLOCK;

    __shared__ int   s_cls[ROWS_PER_BLOCK];
    __shared__ float s_red[4];

    // ---------------- Phase A: one-hot scan, 8 rows ----------------
    if (tid < N_CLASSES / 4) {
        #pragma unroll
        for (int r = 0; r < ROWS_PER_BLOCK; ++r) {
            const int row = row0 + r;
            if (row < n_rows) {
                const floatx4* lrow = (const floatx4*)(labels + (size_t)row * N_CLASSES);
                floatx4 v = __builtin_nontemporal_load(lrow + tid);
                if (v.x != 0.f || v.y != 0.f || v.z != 0.f || v.w != 0.f) {
                    int c = 4 * tid;
                    if      (v.y != 0.f) c += 1;
                    else if (v.z != 0.f) c += 2;
                    else if (v.w != 0.f) c += 3;
                    s_cls[r] = c;          // exactly one writer per row
                }
            }
        }
    }

    // Feature loads for this wave's two rows — independent of the barrier,
    // issued now so they overlap the phase-A drain.
    const int rA = row0 + 2 * wave;
    const int rB = rA + 1;
    const bool okA = rA < n_rows, okB = rB < n_rows;

    const floatx4* fArow = (const floatx4*)(features + (size_t)(okA ? rA : 0) * EMBED);
    const floatx4* fBrow = (const floatx4*)(features + (size_t)(okB ? rB : 0) * EMBED);
    floatx4 a0 = __builtin_nontemporal_load(fArow + lane);
    floatx4 a1 = __builtin_nontemporal_load(fArow + lane + 64);
    floatx4 a2 = __builtin_nontemporal_load(fArow + lane + 128);
    floatx4 a3 = __builtin_nontemporal_load(fArow + lane + 192);
    floatx4 b0 = __builtin_nontemporal_load(fBrow + lane);
    floatx4 b1 = __builtin_nontemporal_load(fBrow + lane + 64);
    floatx4 b2 = __builtin_nontemporal_load(fBrow + lane + 128);
    floatx4 b3 = __builtin_nontemporal_load(fBrow + lane + 192);

    __syncthreads();

    // ---------------- Phase B: proto gather + dots ----------------
    const int clsA = okA ? s_cls[2 * wave] : 0;
    const int clsB = okB ? s_cls[2 * wave + 1] : 0;
    const floatx4* pArow = (const floatx4*)(mean_class + (size_t)clsA * EMBED);
    const floatx4* pBrow = (const floatx4*)(mean_class + (size_t)clsB * EMBED);
    floatx4 pa0 = pArow[lane];
    floatx4 pa1 = pArow[lane + 64];
    floatx4 pa2 = pArow[lane + 128];
    floatx4 pa3 = pArow[lane + 192];
    floatx4 pb0 = pBrow[lane];
    floatx4 pb1 = pBrow[lane + 64];
    floatx4 pb2 = pBrow[lane + 128];
    floatx4 pb3 = pBrow[lane + 192];

    float ffA = 0.f, ppA = 0.f, fpA = 0.f;
    float ffB = 0.f, ppB = 0.f, fpB = 0.f;
    #define DOT3(FF, PP, FP, F, P) \
        FF += F.x*F.x + F.y*F.y + F.z*F.z + F.w*F.w; \
        PP += P.x*P.x + P.y*P.y + P.z*P.z + P.w*P.w; \
        FP += F.x*P.x + F.y*P.y + F.z*P.z + F.w*P.w;
    DOT3(ffA, ppA, fpA, a0, pa0) DOT3(ffA, ppA, fpA, a1, pa1)
    DOT3(ffA, ppA, fpA, a2, pa2) DOT3(ffA, ppA, fpA, a3, pa3)
    DOT3(ffB, ppB, fpB, b0, pb0) DOT3(ffB, ppB, fpB, b1, pb1)
    DOT3(ffB, ppB, fpB, b2, pb2) DOT3(ffB, ppB, fpB, b3, pb3)
    #undef DOT3

    #pragma unroll
    for (int msk = 1; msk < 64; msk <<= 1) {
        ffA += __shfl_xor(ffA, msk, 64);
        ppA += __shfl_xor(ppA, msk, 64);
        fpA += __shfl_xor(fpA, msk, 64);
        ffB += __shfl_xor(ffB, msk, 64);
        ppB += __shfl_xor(ppB, msk, 64);
        fpB += __shfl_xor(fpB, msk, 64);
    }

    float res = 0.f;
    if (okA) res += 1.0f - fpA / (fmaxf(sqrtf(ffA), 1e-12f) * fmaxf(sqrtf(ppA), 1e-12f));
    if (okB) res += 1.0f - fpB / (fmaxf(sqrtf(ffB), 1e-12f) * fmaxf(sqrtf(ppB), 1e-12f));

    if (lane == 0) s_red[wave] = res;
    __syncthreads();
    if (tid == 0)
        partials[blockIdx.x] = s_red[0] + s_red[1] + s_red[2] + s_red[3];
}

__global__ __launch_bounds__(256) void reduce_partials_kernel(
    const float* __restrict__ partials, int num_partials,
    float* __restrict__ out, float inv_n)
{
    const int tid  = threadIdx.x;
    const int lane = tid & 63;
    const int wave = tid >> 6;
    __shared__ float s_red[4];

    float acc = 0.0f;
    for (int i = tid; i < num_partials; i += 256)
        acc += partials[i];
    #pragma unroll
    for (int msk = 1; msk < 64; msk <<= 1)
        acc += __shfl_xor(acc, msk, 64);
    if (lane == 0) s_red[wave] = acc;
    __syncthreads();
    if (tid == 0)
        out[0] = (s_red[0] + s_red[1] + s_red[2] + s_red[3]) * inv_n;
}

extern "C" void kernel_launch(void* const* d_in, const int* in_sizes, int n_in,
                              void* d_out, int out_size, void* d_ws, size_t ws_size,
                              hipStream_t stream) {
    const float* features   = (const float*)d_in[0];
    const float* labels     = (const float*)d_in[1];
    const float* mean_class = (const float*)d_in[2];
    float* out = (float*)d_out;
    float* partials = (float*)d_ws;

    const int n_rows = in_sizes[0] / EMBED;                       // 32768
    const int num_blocks = (n_rows + ROWS_PER_BLOCK - 1) / ROWS_PER_BLOCK;  // 4096

    angular_fused_kernel<<<num_blocks, 256, 0, stream>>>(
        features, labels, mean_class, partials, n_rows);
    reduce_partials_kernel<<<1, 256, 0, stream>>>(
        partials, num_blocks, out, 1.0f / (float)n_rows);
}